// Round 1
// baseline (566.166 us; speedup 1.0000x reference)
//
#include <hip/hip_runtime.h>
#include <stdint.h>

#define LL 4096
#define NB 2
#define KK 30
#define FDIM 167
#define CDIM 128

__device__ __forceinline__ float3 loadCa(const float* __restrict__ Ca, int b, int idx) {
    const float* p = Ca + ((size_t)(b * LL + idx)) * 3;
    return make_float3(p[0], p[1], p[2]);
}
// sel: 0 -> Ca_0 (prev, zero at i==0), 1 -> Ca, 2 -> Ca_2 (next, zero at i==L-1)
__device__ __forceinline__ float3 shiftedCa(const float* __restrict__ Ca, int b, int idx, int sel) {
    int jj = idx + sel - 1;
    if (jj < 0 || jj >= LL) return make_float3(0.f, 0.f, 0.f);
    return loadCa(Ca, b, jj);
}
__device__ __forceinline__ float sgnf(float x) { return (x > 0.f) ? 1.f : ((x < 0.f) ? -1.f : 0.f); }

// ---------------- W transpose: Wt[f][c] = W[c][f] ----------------
__global__ __launch_bounds__(256) void wt_kernel(const float* __restrict__ W, float* __restrict__ Wt) {
    int t = blockIdx.x * 256 + threadIdx.x;
    if (t < CDIM * FDIM) {
        int c = t / FDIM, f = t % FDIM;
        Wt[f * CDIM + c] = W[t];
    }
}

// ---------------- local frames O[b,i][9] ----------------
__global__ __launch_bounds__(256) void frames_kernel(const float* __restrict__ Ca, float* __restrict__ Of) {
    int t = blockIdx.x * 256 + threadIdx.x;
    if (t >= NB * LL) return;
    int b = t >> 12, i = t & (LL - 1);
    float o[9] = {0.f, 0.f, 0.f, 0.f, 0.f, 0.f, 0.f, 0.f, 0.f};
    if (i >= 1 && i <= LL - 3) {
        float3 cm = loadCa(Ca, b, i - 1), cc = loadCa(Ca, b, i), cp = loadCa(Ca, b, i + 1);
        float dx0 = cc.x - cm.x, dy0 = cc.y - cm.y, dz0 = cc.z - cm.z;
        float n0 = sqrtf(dx0 * dx0 + dy0 * dy0 + dz0 * dz0);
        float k0 = (n0 > 3.6f && n0 < 4.0f) ? 1.f : 0.f;
        float s0 = k0 / fmaxf(n0 * k0, 1e-12f);
        float u2x = dx0 * s0, u2y = dy0 * s0, u2z = dz0 * s0;
        float dx1 = cp.x - cc.x, dy1 = cp.y - cc.y, dz1 = cp.z - cc.z;
        float n1 = sqrtf(dx1 * dx1 + dy1 * dy1 + dz1 * dz1);
        float k1 = (n1 > 3.6f && n1 < 4.0f) ? 1.f : 0.f;
        float s1 = k1 / fmaxf(n1 * k1, 1e-12f);
        float u1x = dx1 * s1, u1y = dy1 * s1, u1z = dz1 * s1;
        // n2 = normalize(cross(u2,u1))
        float cx = u2y * u1z - u2z * u1y;
        float cy = u2z * u1x - u2x * u1z;
        float cz = u2x * u1y - u2y * u1x;
        float cn = sqrtf(cx * cx + cy * cy + cz * cz);
        float cinv = 1.f / fmaxf(cn, 1e-12f);
        float n2x = cx * cinv, n2y = cy * cinv, n2z = cz * cinv;
        // o1 = normalize(u2 - u1)
        float ox = u2x - u1x, oy = u2y - u1y, oz = u2z - u1z;
        float on = sqrtf(ox * ox + oy * oy + oz * oz);
        float oinv = 1.f / fmaxf(on, 1e-12f);
        float o1x = ox * oinv, o1y = oy * oinv, o1z = oz * oinv;
        // row2 = cross(o1, n2) (NOT normalized)
        float r2x = o1y * n2z - o1z * n2y;
        float r2y = o1z * n2x - o1x * n2z;
        float r2z = o1x * n2y - o1y * n2x;
        o[0] = o1x; o[1] = o1y; o[2] = o1z;
        o[3] = n2x; o[4] = n2y; o[5] = n2z;
        o[6] = r2x; o[7] = r2y; o[8] = r2z;
    }
    float* dst = Of + (size_t)t * 9;
#pragma unroll
    for (int r = 0; r < 9; r++) dst[r] = o[r];
}

// ---------------- top-K per row ----------------
// key = (fp32 bits of D_adjust << 32) | j  -> uint64 min == (min value, then min index),
// exactly jax.lax.top_k(-D) order (ascending distance, ties -> lower index).
__global__ __launch_bounds__(256) void topk_kernel(const float* __restrict__ Ca,
                                                   const float* __restrict__ mask,
                                                   int* __restrict__ eidx_ws,
                                                   float* __restrict__ dnb_ws,
                                                   float* __restrict__ out_eidx_f) {
    __shared__ unsigned long long keys[LL];
    __shared__ unsigned long long tmin[256];
    __shared__ unsigned long long warpmin[4];
    __shared__ unsigned long long winner;
    __shared__ float wmax[4];
    int row = blockIdx.x;  // b*L + i
    int b = row >> 12;
    int tid = threadIdx.x;
    float3 ci = loadCa(Ca, b, row & (LL - 1));
    float mi = mask[row];
    float dreg[16];
    float mreg[16];
    float localmax = 0.f;
#pragma unroll
    for (int s = 0; s < 16; s++) {
        int j = tid + s * 256;
        const float* pj = Ca + ((size_t)(b * LL + j)) * 3;
        float dx = pj[0] - ci.x, dy = pj[1] - ci.y, dz = pj[2] - ci.z;
        float d = sqrtf(dx * dx + dy * dy + dz * dz + 1e-6f);
        float m2 = mi * mask[b * LL + j];
        float D = m2 * d;
        dreg[s] = D;
        mreg[s] = m2;
        localmax = fmaxf(localmax, D);
    }
#pragma unroll
    for (int o = 32; o; o >>= 1) localmax = fmaxf(localmax, __shfl_xor(localmax, o));
    if ((tid & 63) == 0) wmax[tid >> 6] = localmax;
    __syncthreads();
    float dmax = fmaxf(fmaxf(wmax[0], wmax[1]), fmaxf(wmax[2], wmax[3]));
    unsigned long long lmin = ~0ull;
#pragma unroll
    for (int s = 0; s < 16; s++) {
        int j = tid + s * 256;
        float dadj = dreg[s] + (1.0f - mreg[s]) * dmax;
        unsigned long long key = ((unsigned long long)__float_as_uint(dadj) << 32) | (unsigned)j;
        keys[j] = key;
        if (key < lmin) lmin = key;
    }
    tmin[tid] = lmin;
    __syncthreads();
    for (int t = 0; t < KK; t++) {
        unsigned long long v = tmin[tid];
#pragma unroll
        for (int o = 32; o; o >>= 1) {
            unsigned long long u = __shfl_xor(v, o);
            if (u < v) v = u;
        }
        if ((tid & 63) == 0) warpmin[tid >> 6] = v;
        __syncthreads();
        if (tid == 0) {
            unsigned long long w = warpmin[0];
#pragma unroll
            for (int q = 1; q < 4; q++)
                if (warpmin[q] < w) w = warpmin[q];
            winner = w;
            int j = (int)(w & 0xffffffffu);
            float dv = __uint_as_float((unsigned)(w >> 32));
            eidx_ws[row * KK + t] = j;
            dnb_ws[row * KK + t] = dv;
            out_eidx_f[row * KK + t] = (float)j;  // harness reads whole d_out as fp32
        }
        __syncthreads();
        int j = (int)(winner & 0xffffffffu);
        if ((j & 255) == tid) {
            keys[j] = ~0ull;
            unsigned long long nm = ~0ull;
#pragma unroll
            for (int s = 0; s < 16; s++) {
                unsigned long long kk = keys[tid + s * 256];
                if (kk < nm) nm = kk;
            }
            tmin[tid] = nm;
        }
        __syncthreads();
    }
}

// ---------------- per-row edge features + 167x128 matvec + LayerNorm ----------------
__global__ __launch_bounds__(256) void edge_kernel(const float* __restrict__ Ca,
                                                   const int* __restrict__ ridx,
                                                   const int* __restrict__ chl,
                                                   const float* __restrict__ posW,
                                                   const float* __restrict__ posb,
                                                   const float* __restrict__ Wt,  // [167][128]
                                                   const float* __restrict__ ln_g,
                                                   const float* __restrict__ ln_b,
                                                   const float* __restrict__ Of,
                                                   const int* __restrict__ eidx_ws,
                                                   const float* __restrict__ dnb_ws,
                                                   float* __restrict__ outE) {
    __shared__ float featT[FDIM + 1][32];  // f-major, cols = edge k (30 used)
    int row = blockIdx.x;
    int b = row >> 12, i = row & (LL - 1);
    int tid = threadIdx.x;
    int k = tid & 31, slot = tid >> 5;

    if (k < KK) {
        int j = eidx_ws[row * KK + k];
        for (int task = slot; task < 11; task += 8) {
            if (task == 0) {
                // positional (one-hot @ pos_W.T + pos_b  ==  pos_W[:,d] + pos_b)
                int off = ridx[row] - ridx[b * LL + j];
                int eq = (chl[row] == chl[b * LL + j]) ? 1 : 0;
                int d = off + 32;
                d = d < 0 ? 0 : (d > 64 ? 64 : d);
                d = eq ? d : 65;
#pragma unroll
                for (int p = 0; p < 16; p++) featT[p][k] = posW[p * 66 + d] + posb[p];
            } else if (task <= 9) {
                int q = task - 1;  // RBF group
                float D;
                if (q == 0) {
                    D = dnb_ws[row * KK + k];
                } else {
                    const int asel[8] = {0, 2, 0, 0, 1, 1, 2, 2};
                    const int bsel[8] = {0, 2, 1, 2, 0, 2, 0, 1};
                    float3 A = shiftedCa(Ca, b, i, asel[q - 1]);
                    float3 Bc = shiftedCa(Ca, b, j, bsel[q - 1]);
                    float dx = A.x - Bc.x, dy = A.y - Bc.y, dz = A.z - Bc.z;
                    D = sqrtf(dx * dx + dy * dy + dz * dz + 1e-6f);
                }
#pragma unroll
                for (int m = 0; m < 16; m++) {
                    float mu = 2.0f + (20.0f / 15.0f) * (float)m;
                    float tt = (D - mu) * 0.8f;  // /1.25
                    featT[16 + q * 16 + m][k] = expf(-tt * tt);
                }
            } else {
                // orientation: dU (3) + quaternion (4)
                float Oi[9], Oj[9];
#pragma unroll
                for (int r = 0; r < 9; r++) {
                    Oi[r] = Of[(size_t)row * 9 + r];
                    Oj[r] = Of[((size_t)(b * LL + j)) * 9 + r];
                }
                float3 cj = loadCa(Ca, b, j), cii = loadCa(Ca, b, i);
                float dx = cj.x - cii.x, dy = cj.y - cii.y, dz = cj.z - cii.z;
                float v0 = Oi[0] * dx + Oi[1] * dy + Oi[2] * dz;
                float v1 = Oi[3] * dx + Oi[4] * dy + Oi[5] * dz;
                float v2 = Oi[6] * dx + Oi[7] * dy + Oi[8] * dz;
                float nn = sqrtf(v0 * v0 + v1 * v1 + v2 * v2);
                float ninv = 1.f / fmaxf(nn, 1e-12f);
                featT[160][k] = v0 * ninv;
                featT[161][k] = v1 * ninv;
                featT[162][k] = v2 * ninv;
                // R = Oi^T @ Oj
                float R[3][3];
#pragma unroll
                for (int m = 0; m < 3; m++)
#pragma unroll
                    for (int n = 0; n < 3; n++)
                        R[m][n] = Oi[0 * 3 + m] * Oj[0 * 3 + n] + Oi[1 * 3 + m] * Oj[1 * 3 + n] +
                                  Oi[2 * 3 + m] * Oj[2 * 3 + n];
                float Rxx = R[0][0], Ryy = R[1][1], Rzz = R[2][2];
                float m0 = 0.5f * sqrtf(fabsf(1.f + Rxx - Ryy - Rzz));
                float m1 = 0.5f * sqrtf(fabsf(1.f - Rxx + Ryy - Rzz));
                float m2 = 0.5f * sqrtf(fabsf(1.f - Rxx - Ryy + Rzz));
                float x = sgnf(R[2][1] - R[1][2]) * m0;
                float y = sgnf(R[0][2] - R[2][0]) * m1;
                float z = sgnf(R[1][0] - R[0][1]) * m2;
                float w = 0.5f * sqrtf(fmaxf(1.f + Rxx + Ryy + Rzz, 0.f));
                float qn = sqrtf(x * x + y * y + z * z + w * w);
                float qi = 1.f / fmaxf(qn, 1e-12f);
                featT[163][k] = x * qi;
                featT[164][k] = y * qi;
                featT[165][k] = z * qi;
                featT[166][k] = w * qi;
            }
        }
    }
    __syncthreads();

    // matvec: thread (te, tc) computes edges {2te, 2te+1} x channels [8tc, 8tc+8)
    int tc = tid & 15, te = tid >> 4;  // te 0..15, te==15 idle
    float acc[2][8];
#pragma unroll
    for (int e = 0; e < 2; e++)
#pragma unroll
        for (int c = 0; c < 8; c++) acc[e][c] = 0.f;

    if (te < 15) {
        const float2* fT2 = (const float2*)featT;  // row = 16 float2
        for (int f = 0; f < FDIM; f++) {
            float2 fe = fT2[f * 16 + te];
            float4 w0 = *(const float4*)(Wt + f * CDIM + tc * 8);
            float4 w1 = *(const float4*)(Wt + f * CDIM + tc * 8 + 4);
            acc[0][0] += fe.x * w0.x; acc[0][1] += fe.x * w0.y;
            acc[0][2] += fe.x * w0.z; acc[0][3] += fe.x * w0.w;
            acc[0][4] += fe.x * w1.x; acc[0][5] += fe.x * w1.y;
            acc[0][6] += fe.x * w1.z; acc[0][7] += fe.x * w1.w;
            acc[1][0] += fe.y * w0.x; acc[1][1] += fe.y * w0.y;
            acc[1][2] += fe.y * w0.z; acc[1][3] += fe.y * w0.w;
            acc[1][4] += fe.y * w1.x; acc[1][5] += fe.y * w1.y;
            acc[1][6] += fe.y * w1.z; acc[1][7] += fe.y * w1.w;
        }
        float4 lg0 = *(const float4*)(ln_g + tc * 8);
        float4 lg1 = *(const float4*)(ln_g + tc * 8 + 4);
        float4 lb0 = *(const float4*)(ln_b + tc * 8);
        float4 lb1 = *(const float4*)(ln_b + tc * 8 + 4);
        float lg[8] = {lg0.x, lg0.y, lg0.z, lg0.w, lg1.x, lg1.y, lg1.z, lg1.w};
        float lb[8] = {lb0.x, lb0.y, lb0.z, lb0.w, lb1.x, lb1.y, lb1.z, lb1.w};
#pragma unroll
        for (int e = 0; e < 2; e++) {
            float s = 0.f;
#pragma unroll
            for (int c = 0; c < 8; c++) s += acc[e][c];
#pragma unroll
            for (int o = 1; o < 16; o <<= 1) s += __shfl_xor(s, o);
            float mu = s * (1.f / 128.f);
            float vs = 0.f;
#pragma unroll
            for (int c = 0; c < 8; c++) {
                float d = acc[e][c] - mu;
                vs += d * d;
            }
#pragma unroll
            for (int o = 1; o < 16; o <<= 1) vs += __shfl_xor(vs, o);
            float var = vs * (1.f / 128.f);
            float invs = 1.f / sqrtf(var + 1e-5f);
            int edge = 2 * te + e;
            float* dst = outE + ((size_t)row * KK + edge) * CDIM + tc * 8;
            float4 r0, r1;
            r0.x = (acc[e][0] - mu) * invs * lg[0] + lb[0];
            r0.y = (acc[e][1] - mu) * invs * lg[1] + lb[1];
            r0.z = (acc[e][2] - mu) * invs * lg[2] + lb[2];
            r0.w = (acc[e][3] - mu) * invs * lg[3] + lb[3];
            r1.x = (acc[e][4] - mu) * invs * lg[4] + lb[4];
            r1.y = (acc[e][5] - mu) * invs * lg[5] + lb[5];
            r1.z = (acc[e][6] - mu) * invs * lg[6] + lb[6];
            r1.w = (acc[e][7] - mu) * invs * lg[7] + lb[7];
            *(float4*)dst = r0;
            *(float4*)(dst + 4) = r1;
        }
    }
}

extern "C" void kernel_launch(void* const* d_in, const int* in_sizes, int n_in,
                              void* d_out, int out_size, void* d_ws, size_t ws_size,
                              hipStream_t stream) {
    const float* Ca = (const float*)d_in[0];
    const float* mask = (const float*)d_in[1];
    const int* ridx = (const int*)d_in[2];
    const int* chl = (const int*)d_in[3];
    const float* posW = (const float*)d_in[4];
    const float* posb = (const float*)d_in[5];
    const float* edgeW = (const float*)d_in[6];
    const float* lng = (const float*)d_in[7];
    const float* lnb = (const float*)d_in[8];

    float* outE = (float*)d_out;
    float* outEidxF = outE + (size_t)NB * LL * KK * CDIM;

    char* ws = (char*)d_ws;
    float* Wt = (float*)ws;                                   // 167*128*4 = 85504 B
    float* Of = (float*)(ws + 85504);                         // 2*4096*9*4 = 294912 B
    int* eidx = (int*)(ws + 85504 + 294912);                  // 983040 B
    float* dnb = (float*)(ws + 85504 + 294912 + 983040);      // 983040 B

    wt_kernel<<<(CDIM * FDIM + 255) / 256, 256, 0, stream>>>(edgeW, Wt);
    frames_kernel<<<(NB * LL + 255) / 256, 256, 0, stream>>>(Ca, Of);
    topk_kernel<<<NB * LL, 256, 0, stream>>>(Ca, mask, eidx, dnb, outEidxF);
    edge_kernel<<<NB * LL, 256, 0, stream>>>(Ca, ridx, chl, posW, posb, Wt, lng, lnb,
                                             Of, eidx, dnb, outE);
}

// Round 2
// 385.603 us; speedup vs baseline: 1.4683x; 1.4683x over previous
//
#include <hip/hip_runtime.h>
#include <stdint.h>

#define LL 4096
#define NB 2
#define KK 30
#define CDIM 128
#define FROW 200  // feat row stride in halves (400 B, multiple of 16 B)

typedef _Float16 half_t;
typedef half_t half8 __attribute__((ext_vector_type(8)));
typedef float f32x4 __attribute__((ext_vector_type(4)));

__device__ __forceinline__ float3 loadCa(const float* __restrict__ Ca, int b, int idx) {
    const float* p = Ca + ((size_t)(b * LL + idx)) * 3;
    return make_float3(p[0], p[1], p[2]);
}
__device__ __forceinline__ float3 shiftedCa(const float* __restrict__ Ca, int b, int idx, int sel) {
    int jj = idx + sel - 1;
    if (jj < 0 || jj >= LL) return make_float3(0.f, 0.f, 0.f);
    return loadCa(Ca, b, jj);
}
__device__ __forceinline__ float sgnf(float x) { return (x > 0.f) ? 1.f : ((x < 0.f) ? -1.f : 0.f); }

// ---------------- pack W into B-fragment order (f16) ----------------
// Bp[((t*6+s)*64 + l)*8 + e] = W[n=16t+(l&15)][k=32s+8*(l>>4)+e], 0 if k>=167
__global__ __launch_bounds__(256) void pack_kernel(const float* __restrict__ W, half_t* __restrict__ Bp) {
    int idx = blockIdx.x * 256 + threadIdx.x;
    if (idx >= 8 * 6 * 64) return;
    int l = idx & 63;
    int ts = idx >> 6;
    int s = ts % 6, t = ts / 6;
    int n = 16 * t + (l & 15);
    int kbase = 32 * s + 8 * (l >> 4);
    half8 v;
#pragma unroll
    for (int e = 0; e < 8; e++) {
        int k = kbase + e;
        v[e] = (k < 167) ? (half_t)W[n * 167 + k] : (half_t)0.f;
    }
    *(half8*)(Bp + (size_t)idx * 8) = v;
}

// ---------------- local frames O[b,i][9] ----------------
__global__ __launch_bounds__(256) void frames_kernel(const float* __restrict__ Ca, float* __restrict__ Of) {
    int t = blockIdx.x * 256 + threadIdx.x;
    if (t >= NB * LL) return;
    int b = t >> 12, i = t & (LL - 1);
    float o[9] = {0.f, 0.f, 0.f, 0.f, 0.f, 0.f, 0.f, 0.f, 0.f};
    if (i >= 1 && i <= LL - 3) {
        float3 cm = loadCa(Ca, b, i - 1), cc = loadCa(Ca, b, i), cp = loadCa(Ca, b, i + 1);
        float dx0 = cc.x - cm.x, dy0 = cc.y - cm.y, dz0 = cc.z - cm.z;
        float n0 = sqrtf(dx0 * dx0 + dy0 * dy0 + dz0 * dz0);
        float k0 = (n0 > 3.6f && n0 < 4.0f) ? 1.f : 0.f;
        float s0 = k0 / fmaxf(n0 * k0, 1e-12f);
        float u2x = dx0 * s0, u2y = dy0 * s0, u2z = dz0 * s0;
        float dx1 = cp.x - cc.x, dy1 = cp.y - cc.y, dz1 = cp.z - cc.z;
        float n1 = sqrtf(dx1 * dx1 + dy1 * dy1 + dz1 * dz1);
        float k1 = (n1 > 3.6f && n1 < 4.0f) ? 1.f : 0.f;
        float s1 = k1 / fmaxf(n1 * k1, 1e-12f);
        float u1x = dx1 * s1, u1y = dy1 * s1, u1z = dz1 * s1;
        float cx = u2y * u1z - u2z * u1y;
        float cy = u2z * u1x - u2x * u1z;
        float cz = u2x * u1y - u2y * u1x;
        float cn = sqrtf(cx * cx + cy * cy + cz * cz);
        float cinv = 1.f / fmaxf(cn, 1e-12f);
        float n2x = cx * cinv, n2y = cy * cinv, n2z = cz * cinv;
        float ox = u2x - u1x, oy = u2y - u1y, oz = u2z - u1z;
        float on = sqrtf(ox * ox + oy * oy + oz * oz);
        float oinv = 1.f / fmaxf(on, 1e-12f);
        float o1x = ox * oinv, o1y = oy * oinv, o1z = oz * oinv;
        float r2x = o1y * n2z - o1z * n2y;
        float r2y = o1z * n2x - o1x * n2z;
        float r2z = o1x * n2y - o1y * n2x;
        o[0] = o1x; o[1] = o1y; o[2] = o1z;
        o[3] = n2x; o[4] = n2y; o[5] = n2z;
        o[6] = r2x; o[7] = r2y; o[8] = r2z;
    }
    float* dst = Of + (size_t)t * 9;
#pragma unroll
    for (int r = 0; r < 9; r++) dst[r] = o[r];
}

// ---------------- top-K per row: per-wave extract + merge ----------------
__global__ __launch_bounds__(256) void topk_kernel(const float* __restrict__ Ca,
                                                   const float* __restrict__ mask,
                                                   int* __restrict__ eidx_ws,
                                                   float* __restrict__ dnb_ws,
                                                   float* __restrict__ out_eidx_f) {
    __shared__ unsigned long long keys[LL];
    __shared__ unsigned long long wcand[4 * KK];
    __shared__ float wmaxs[4];
    int row = blockIdx.x;
    int b = row >> 12;
    int tid = threadIdx.x;
    int w = tid >> 6, lane = tid & 63;
    int jbase = w * 1024 + lane;
    float3 ci = loadCa(Ca, b, row & (LL - 1));
    float mi = mask[row];
    float dreg[16], mreg[16];
    float localmax = 0.f;
#pragma unroll
    for (int s = 0; s < 16; s++) {
        int j = jbase + 64 * s;
        const float* pj = Ca + ((size_t)(b * LL + j)) * 3;
        float dx = pj[0] - ci.x, dy = pj[1] - ci.y, dz = pj[2] - ci.z;
        float d = sqrtf(dx * dx + dy * dy + dz * dz + 1e-6f);
        float m2 = mi * mask[b * LL + j];
        float D = m2 * d;
        dreg[s] = D;
        mreg[s] = m2;
        localmax = fmaxf(localmax, D);
    }
#pragma unroll
    for (int o = 32; o; o >>= 1) localmax = fmaxf(localmax, __shfl_xor(localmax, o));
    if (lane == 0) wmaxs[w] = localmax;
    __syncthreads();
    float dmax = fmaxf(fmaxf(wmaxs[0], wmaxs[1]), fmaxf(wmaxs[2], wmaxs[3]));
    unsigned long long lmin = ~0ull;
#pragma unroll
    for (int s = 0; s < 16; s++) {
        int j = jbase + 64 * s;
        float dadj = dreg[s] + (1.0f - mreg[s]) * dmax;
        unsigned long long key = ((unsigned long long)__float_as_uint(dadj) << 32) | (unsigned)j;
        keys[j] = key;
        if (key < lmin) lmin = key;
    }
    __syncthreads();
    // per-wave top-30 over its 1024 slice; no barriers (shuffle bcast, owner-only LDS)
    for (int t = 0; t < KK; t++) {
        unsigned long long v = lmin;
#pragma unroll
        for (int o = 32; o; o >>= 1) {
            unsigned long long u = __shfl_xor(v, o);
            if (u < v) v = u;
        }
        if (lane == 0) wcand[w * KK + t] = v;
        int j = (int)(v & 0xffffffffu);
        if ((j & 63) == lane) {
            keys[j] = ~0ull;
            unsigned long long nm = ~0ull;
#pragma unroll
            for (int s = 0; s < 16; s++) {
                unsigned long long kk = keys[jbase + 64 * s];
                if (kk < nm) nm = kk;
            }
            lmin = nm;
        }
    }
    __syncthreads();
    if (w == 0) {
        unsigned long long c0 = (lane < 120) ? wcand[lane] : ~0ull;
        unsigned long long c1 = (lane < 56) ? wcand[64 + lane] : ~0ull;
        for (int t = 0; t < KK; t++) {
            unsigned long long v = (c0 < c1) ? c0 : c1;
#pragma unroll
            for (int o = 32; o; o >>= 1) {
                unsigned long long u = __shfl_xor(v, o);
                if (u < v) v = u;
            }
            if (lane == 0) {
                int j = (int)(v & 0xffffffffu);
                float dv = __uint_as_float((unsigned)(v >> 32));
                eidx_ws[row * KK + t] = j;
                dnb_ws[row * KK + t] = dv;
                out_eidx_f[row * KK + t] = (float)j;
            }
            if (c0 == v) c0 = ~0ull;
            if (c1 == v) c1 = ~0ull;
        }
    }
}

// ---------------- features (f16, LDS) + MFMA 64x128x192 + LayerNorm ----------------
__global__ __launch_bounds__(256) void edge_kernel(const float* __restrict__ Ca,
                                                   const int* __restrict__ ridx,
                                                   const int* __restrict__ chl,
                                                   const float* __restrict__ posW,
                                                   const float* __restrict__ posb,
                                                   const half_t* __restrict__ Bp,
                                                   const float* __restrict__ ln_g,
                                                   const float* __restrict__ ln_b,
                                                   const float* __restrict__ Of,
                                                   const int* __restrict__ eidx_ws,
                                                   const float* __restrict__ dnb_ws,
                                                   float* __restrict__ outE) {
    __shared__ alignas(16) half_t featH[64][FROW];
    int row0 = blockIdx.x * 2;
    int b = row0 >> 12;
    int tid = threadIdx.x;

    // zero K-pad [167,200) for all rows, and dummy rows 60..63 entirely
    for (int idx = tid; idx < 64 * 33; idx += 256) {
        int e = idx / 33;
        featH[e][167 + idx % 33] = (half_t)0.f;
    }
    for (int idx = tid; idx < 4 * FROW; idx += 256) {
        featH[60 + idx / FROW][idx % FROW] = (half_t)0.f;
    }

    int e = tid >> 2, slot = tid & 3;
    if (e < 60) {
        int grow = row0 + (e >= KK ? 1 : 0);
        int ke = e - (e >= KK ? KK : 0);
        int i = grow & (LL - 1);
        int j = eidx_ws[grow * KK + ke];
        for (int task = slot; task < 11; task += 4) {
            if (task == 0) {
                int off = ridx[grow] - ridx[b * LL + j];
                int eq = (chl[grow] == chl[b * LL + j]) ? 1 : 0;
                int d = off + 32;
                d = d < 0 ? 0 : (d > 64 ? 64 : d);
                d = eq ? d : 65;
#pragma unroll
                for (int p = 0; p < 16; p++) featH[e][p] = (half_t)(posW[p * 66 + d] + posb[p]);
            } else if (task <= 9) {
                int q = task - 1;
                float D;
                if (q == 0) {
                    D = dnb_ws[grow * KK + ke];
                } else {
                    const int asel[8] = {0, 2, 0, 0, 1, 1, 2, 2};
                    const int bsel[8] = {0, 2, 1, 2, 0, 2, 0, 1};
                    float3 A = shiftedCa(Ca, b, i, asel[q - 1]);
                    float3 Bc = shiftedCa(Ca, b, j, bsel[q - 1]);
                    float dx = A.x - Bc.x, dy = A.y - Bc.y, dz = A.z - Bc.z;
                    D = sqrtf(dx * dx + dy * dy + dz * dz + 1e-6f);
                }
#pragma unroll
                for (int m = 0; m < 16; m++) {
                    float mu = 2.0f + (20.0f / 15.0f) * (float)m;
                    float tt = (D - mu) * 0.8f;
                    featH[e][16 + q * 16 + m] = (half_t)expf(-tt * tt);
                }
            } else {
                float Oi[9], Oj[9];
#pragma unroll
                for (int r = 0; r < 9; r++) {
                    Oi[r] = Of[(size_t)grow * 9 + r];
                    Oj[r] = Of[((size_t)(b * LL + j)) * 9 + r];
                }
                float3 cj = loadCa(Ca, b, j), cii = loadCa(Ca, b, i);
                float dx = cj.x - cii.x, dy = cj.y - cii.y, dz = cj.z - cii.z;
                float v0 = Oi[0] * dx + Oi[1] * dy + Oi[2] * dz;
                float v1 = Oi[3] * dx + Oi[4] * dy + Oi[5] * dz;
                float v2 = Oi[6] * dx + Oi[7] * dy + Oi[8] * dz;
                float nn = sqrtf(v0 * v0 + v1 * v1 + v2 * v2);
                float ninv = 1.f / fmaxf(nn, 1e-12f);
                featH[e][160] = (half_t)(v0 * ninv);
                featH[e][161] = (half_t)(v1 * ninv);
                featH[e][162] = (half_t)(v2 * ninv);
                float R[3][3];
#pragma unroll
                for (int m = 0; m < 3; m++)
#pragma unroll
                    for (int n = 0; n < 3; n++)
                        R[m][n] = Oi[0 * 3 + m] * Oj[0 * 3 + n] + Oi[1 * 3 + m] * Oj[1 * 3 + n] +
                                  Oi[2 * 3 + m] * Oj[2 * 3 + n];
                float Rxx = R[0][0], Ryy = R[1][1], Rzz = R[2][2];
                float m0 = 0.5f * sqrtf(fabsf(1.f + Rxx - Ryy - Rzz));
                float m1 = 0.5f * sqrtf(fabsf(1.f - Rxx + Ryy - Rzz));
                float m2 = 0.5f * sqrtf(fabsf(1.f - Rxx - Ryy + Rzz));
                float x = sgnf(R[2][1] - R[1][2]) * m0;
                float y = sgnf(R[0][2] - R[2][0]) * m1;
                float z = sgnf(R[1][0] - R[0][1]) * m2;
                float w = 0.5f * sqrtf(fmaxf(1.f + Rxx + Ryy + Rzz, 0.f));
                float qn = sqrtf(x * x + y * y + z * z + w * w);
                float qi = 1.f / fmaxf(qn, 1e-12f);
                featH[e][163] = (half_t)(x * qi);
                featH[e][164] = (half_t)(y * qi);
                featH[e][165] = (half_t)(z * qi);
                featH[e][166] = (half_t)(w * qi);
            }
        }
    }
    __syncthreads();

    int lane = tid & 63, w = tid >> 6;
    int col = lane & 15, g = lane >> 4;
    half8 af[6];
#pragma unroll
    for (int s = 0; s < 6; s++)
        af[s] = *(const half8*)&featH[16 * w + col][32 * s + 8 * g];
    f32x4 zero = {0.f, 0.f, 0.f, 0.f};
    f32x4 acc[8];
#pragma unroll
    for (int t = 0; t < 8; t++) acc[t] = zero;
#pragma unroll
    for (int t = 0; t < 8; t++) {
#pragma unroll
        for (int s = 0; s < 6; s++) {
            half8 bf = *(const half8*)(Bp + ((size_t)((t * 6 + s) * 64 + lane)) * 8);
            acc[t] = __builtin_amdgcn_mfma_f32_16x16x32_f16(af[s], bf, acc[t], 0, 0, 0);
        }
    }
    // LayerNorm over 128 channels per C-row; C/D: col=lane&15 (+16t), row=4*(lane>>4)+q
    float mu[4], invs[4];
#pragma unroll
    for (int q = 0; q < 4; q++) {
        float s = 0.f;
#pragma unroll
        for (int t = 0; t < 8; t++) s += acc[t][q];
#pragma unroll
        for (int o = 1; o < 16; o <<= 1) s += __shfl_xor(s, o);
        mu[q] = s * (1.f / 128.f);
    }
#pragma unroll
    for (int q = 0; q < 4; q++) {
        float vs = 0.f;
#pragma unroll
        for (int t = 0; t < 8; t++) {
            float d = acc[t][q] - mu[q];
            vs += d * d;
        }
#pragma unroll
        for (int o = 1; o < 16; o <<= 1) vs += __shfl_xor(vs, o);
        invs[q] = 1.f / sqrtf(vs * (1.f / 128.f) + 1e-5f);
    }
    float lgv[8], lbv[8];
#pragma unroll
    for (int t = 0; t < 8; t++) {
        lgv[t] = ln_g[16 * t + col];
        lbv[t] = ln_b[16 * t + col];
    }
#pragma unroll
    for (int q = 0; q < 4; q++) {
        int eq = 16 * w + 4 * g + q;
        if (eq < 60) {
            int grow = row0 + (eq >= KK ? 1 : 0);
            int ke = eq - (eq >= KK ? KK : 0);
            float* dst = outE + ((size_t)(grow * KK + ke)) * CDIM + col;
#pragma unroll
            for (int t = 0; t < 8; t++)
                dst[16 * t] = (acc[t][q] - mu[q]) * invs[q] * lgv[t] + lbv[t];
        }
    }
}

extern "C" void kernel_launch(void* const* d_in, const int* in_sizes, int n_in,
                              void* d_out, int out_size, void* d_ws, size_t ws_size,
                              hipStream_t stream) {
    const float* Ca = (const float*)d_in[0];
    const float* mask = (const float*)d_in[1];
    const int* ridx = (const int*)d_in[2];
    const int* chl = (const int*)d_in[3];
    const float* posW = (const float*)d_in[4];
    const float* posb = (const float*)d_in[5];
    const float* edgeW = (const float*)d_in[6];
    const float* lng = (const float*)d_in[7];
    const float* lnb = (const float*)d_in[8];

    float* outE = (float*)d_out;
    float* outEidxF = outE + (size_t)NB * LL * KK * CDIM;

    char* ws = (char*)d_ws;
    half_t* Bp = (half_t*)ws;                             // 8*6*64*8*2 = 49152 B
    float* Of = (float*)(ws + 49152);                     // 2*4096*9*4 = 294912 B
    int* eidx = (int*)(ws + 49152 + 294912);              // 983040 B
    float* dnb = (float*)(ws + 49152 + 294912 + 983040);  // 983040 B

    pack_kernel<<<12, 256, 0, stream>>>(edgeW, Bp);
    frames_kernel<<<(NB * LL + 255) / 256, 256, 0, stream>>>(Ca, Of);
    topk_kernel<<<NB * LL, 256, 0, stream>>>(Ca, mask, eidx, dnb, outEidxF);
    edge_kernel<<<NB * LL / 2, 256, 0, stream>>>(Ca, ridx, chl, posW, posb, Bp, lng, lnb,
                                                 Of, eidx, dnb, outE);
}

// Round 3
// 132.185 us; speedup vs baseline: 4.2831x; 2.9171x over previous
//
#include <hip/hip_runtime.h>
#include <stdint.h>

#define LL 4096
#define NB 2
#define KK 30
#define CDIM 128
#define FROW 200  // feat row stride in halves (400 B, multiple of 16 B)

typedef _Float16 half_t;
typedef half_t half8 __attribute__((ext_vector_type(8)));
typedef float f32x4 __attribute__((ext_vector_type(4)));

__device__ __forceinline__ float3 loadCa(const float* __restrict__ Ca, int b, int idx) {
    const float* p = Ca + ((size_t)(b * LL + idx)) * 3;
    return make_float3(p[0], p[1], p[2]);
}
__device__ __forceinline__ float3 shiftedCa(const float* __restrict__ Ca, int b, int idx, int sel) {
    int jj = idx + sel - 1;
    if (jj < 0 || jj >= LL) return make_float3(0.f, 0.f, 0.f);
    return loadCa(Ca, b, jj);
}
__device__ __forceinline__ float sgnf(float x) { return (x > 0.f) ? 1.f : ((x < 0.f) ? -1.f : 0.f); }

// ---------------- pack W into B-fragment order (f16) ----------------
__global__ __launch_bounds__(256) void pack_kernel(const float* __restrict__ W, half_t* __restrict__ Bp) {
    int idx = blockIdx.x * 256 + threadIdx.x;
    if (idx >= 8 * 6 * 64) return;
    int l = idx & 63;
    int ts = idx >> 6;
    int s = ts % 6, t = ts / 6;
    int n = 16 * t + (l & 15);
    int kbase = 32 * s + 8 * (l >> 4);
    half8 v;
#pragma unroll
    for (int e = 0; e < 8; e++) {
        int k = kbase + e;
        v[e] = (k < 167) ? (half_t)W[n * 167 + k] : (half_t)0.f;
    }
    *(half8*)(Bp + (size_t)idx * 8) = v;
}

// ---------------- local frames O[b,i][9] ----------------
__global__ __launch_bounds__(256) void frames_kernel(const float* __restrict__ Ca, float* __restrict__ Of) {
    int t = blockIdx.x * 256 + threadIdx.x;
    if (t >= NB * LL) return;
    int b = t >> 12, i = t & (LL - 1);
    float o[9] = {0.f, 0.f, 0.f, 0.f, 0.f, 0.f, 0.f, 0.f, 0.f};
    if (i >= 1 && i <= LL - 3) {
        float3 cm = loadCa(Ca, b, i - 1), cc = loadCa(Ca, b, i), cp = loadCa(Ca, b, i + 1);
        float dx0 = cc.x - cm.x, dy0 = cc.y - cm.y, dz0 = cc.z - cm.z;
        float n0 = sqrtf(dx0 * dx0 + dy0 * dy0 + dz0 * dz0);
        float k0 = (n0 > 3.6f && n0 < 4.0f) ? 1.f : 0.f;
        float s0 = k0 / fmaxf(n0 * k0, 1e-12f);
        float u2x = dx0 * s0, u2y = dy0 * s0, u2z = dz0 * s0;
        float dx1 = cp.x - cc.x, dy1 = cp.y - cc.y, dz1 = cp.z - cc.z;
        float n1 = sqrtf(dx1 * dx1 + dy1 * dy1 + dz1 * dz1);
        float k1 = (n1 > 3.6f && n1 < 4.0f) ? 1.f : 0.f;
        float s1 = k1 / fmaxf(n1 * k1, 1e-12f);
        float u1x = dx1 * s1, u1y = dy1 * s1, u1z = dz1 * s1;
        float cx = u2y * u1z - u2z * u1y;
        float cy = u2z * u1x - u2x * u1z;
        float cz = u2x * u1y - u2y * u1x;
        float cn = sqrtf(cx * cx + cy * cy + cz * cz);
        float cinv = 1.f / fmaxf(cn, 1e-12f);
        float n2x = cx * cinv, n2y = cy * cinv, n2z = cz * cinv;
        float ox = u2x - u1x, oy = u2y - u1y, oz = u2z - u1z;
        float on = sqrtf(ox * ox + oy * oy + oz * oz);
        float oinv = 1.f / fmaxf(on, 1e-12f);
        float o1x = ox * oinv, o1y = oy * oinv, o1z = oz * oinv;
        float r2x = o1y * n2z - o1z * n2y;
        float r2y = o1z * n2x - o1x * n2z;
        float r2z = o1x * n2y - o1y * n2x;
        o[0] = o1x; o[1] = o1y; o[2] = o1z;
        o[3] = n2x; o[4] = n2y; o[5] = n2z;
        o[6] = r2x; o[7] = r2y; o[8] = r2z;
    }
    float* dst = Of + (size_t)t * 9;
#pragma unroll
    for (int r = 0; r < 9; r++) dst[r] = o[r];
}

// ---------------- top-K per row: rank-select threshold + bitonic sort ----------------
__global__ __launch_bounds__(256, 8) void topk_kernel(const float* __restrict__ Ca,
                                                      const float* __restrict__ mask,
                                                      int* __restrict__ eidx_ws,
                                                      float* __restrict__ dnb_ws,
                                                      float* __restrict__ out_eidx_f) {
    __shared__ unsigned long long cand[512];
    __shared__ int wint[2][4];
    __shared__ float wflt[4];
    int row = blockIdx.x;
    int b = row >> 12;
    int tid = threadIdx.x;
    int w = tid >> 6, lane = tid & 63;
    float3 ci = loadCa(Ca, b, row & (LL - 1));
    float mi = mask[row];
    float dreg[16];
    float localmax = 0.f;
#pragma unroll
    for (int s = 0; s < 16; s++) {
        int j = tid + s * 256;
        const float* pj = Ca + ((size_t)(b * LL + j)) * 3;
        float dx = pj[0] - ci.x, dy = pj[1] - ci.y, dz = pj[2] - ci.z;
        float d = sqrtf(dx * dx + dy * dy + dz * dz + 1e-6f);
        float D = mi * mask[b * LL + j] * d;
        dreg[s] = D;
        localmax = fmaxf(localmax, D);
    }
#pragma unroll
    for (int o = 32; o; o >>= 1) localmax = fmaxf(localmax, __shfl_xor(localmax, o));
    if (lane == 0) wflt[w] = localmax;
    __syncthreads();
    float dmax = fmaxf(fmaxf(wflt[0], wflt[1]), fmaxf(wflt[2], wflt[3]));
    // dadj bits (positive floats -> uint order == value order)
    unsigned ui[16];
#pragma unroll
    for (int s = 0; s < 16; s++) {
        int j = tid + s * 256;
        float m2 = mi * mask[b * LL + j];
        ui[s] = __float_as_uint(dreg[s] + (1.0f - m2) * dmax);
    }
    // binary search for threshold T: count(bits < T) in [30, 64]
    unsigned lo = 0u, hi = 0x7f800000u, T = 0u;
    bool found = false;
    int p = 0;
    for (int it = 0; it < 24 && !found; ++it) {
        unsigned mid = (lo + hi) >> 1;
        int c = 0;
#pragma unroll
        for (int s = 0; s < 16; s++) c += (ui[s] < mid) ? 1 : 0;
#pragma unroll
        for (int o = 32; o; o >>= 1) c += __shfl_xor(c, o);
        if (lane == 0) wint[p][w] = c;
        __syncthreads();
        c = wint[p][0] + wint[p][1] + wint[p][2] + wint[p][3];
        p ^= 1;
        if (c < 30) lo = mid;
        else if (c > 64) hi = mid;
        else { T = mid; found = true; }
    }
    if (!found) T = hi;
    // gather candidates (bits < T) into LDS via block prefix scan
    int cnt = 0;
#pragma unroll
    for (int s = 0; s < 16; s++) cnt += (ui[s] < T) ? 1 : 0;
    int inc = cnt;
#pragma unroll
    for (int o = 1; o < 64; o <<= 1) {
        int nv = __shfl_up(inc, o);
        if (lane >= o) inc += nv;
    }
    if (lane == 63) wint[0][w] = inc;
    __syncthreads();
    int C = wint[0][0] + wint[0][1] + wint[0][2] + wint[0][3];
    int waveoff = 0;
    for (int q = 0; q < 4; q++) waveoff += (q < w) ? wint[0][q] : 0;
    int slot = waveoff + inc - cnt;
#pragma unroll
    for (int s = 0; s < 16; s++) {
        if (ui[s] < T) {
            int j = tid + s * 256;
            if (slot < 512)
                cand[slot] = ((unsigned long long)ui[s] << 32) | (unsigned)j;
            slot++;
        }
    }
    __syncthreads();
    if (w != 0) return;
    if (C <= 64) {
        // bitonic sort 64 u64 keys across the wave, ascending
        unsigned long long v = (lane < C) ? cand[lane] : ~0ull;
#pragma unroll
        for (int k = 2; k <= 64; k <<= 1) {
#pragma unroll
            for (int jj = k >> 1; jj > 0; jj >>= 1) {
                unsigned long long o = __shfl_xor(v, jj);
                bool take_min = (((lane & jj) == 0) == ((lane & k) == 0));
                bool lt = (o < v);
                v = (take_min == lt) ? o : v;
            }
        }
        if (lane < KK) {
            int j = (int)(v & 0xffffffffu);
            float dv = __uint_as_float((unsigned)(v >> 32));
            eidx_ws[row * KK + lane] = j;
            dnb_ws[row * KK + lane] = dv;
            out_eidx_f[row * KK + lane] = (float)j;
        }
    } else {
        // fallback (needs >=36 bit-identical distances to trigger): extract-min over <=512 cands
        unsigned long long r[8];
#pragma unroll
        for (int q = 0; q < 8; q++) {
            int idx = lane + 64 * q;
            r[q] = (idx < C && idx < 512) ? cand[idx] : ~0ull;
        }
        for (int t = 0; t < KK; t++) {
            unsigned long long v = r[0];
#pragma unroll
            for (int q = 1; q < 8; q++) v = (r[q] < v) ? r[q] : v;
#pragma unroll
            for (int o = 32; o; o >>= 1) {
                unsigned long long u = __shfl_xor(v, o);
                if (u < v) v = u;
            }
            if (lane == 0) {
                int j = (int)(v & 0xffffffffu);
                eidx_ws[row * KK + t] = j;
                dnb_ws[row * KK + t] = __uint_as_float((unsigned)(v >> 32));
                out_eidx_f[row * KK + t] = (float)j;
            }
#pragma unroll
            for (int q = 0; q < 8; q++)
                if (r[q] == v) r[q] = ~0ull;
        }
    }
}

// ---------------- features (f16, LDS) + MFMA 64x128x192 + LayerNorm ----------------
__global__ __launch_bounds__(256) void edge_kernel(const float* __restrict__ Ca,
                                                   const int* __restrict__ ridx,
                                                   const int* __restrict__ chl,
                                                   const float* __restrict__ posW,
                                                   const float* __restrict__ posb,
                                                   const half_t* __restrict__ Bp,
                                                   const float* __restrict__ ln_g,
                                                   const float* __restrict__ ln_b,
                                                   const float* __restrict__ Of,
                                                   const int* __restrict__ eidx_ws,
                                                   const float* __restrict__ dnb_ws,
                                                   float* __restrict__ outE) {
    __shared__ alignas(16) half_t featH[64][FROW];
    int row0 = blockIdx.x * 2;
    int b = row0 >> 12;
    int tid = threadIdx.x;

    for (int idx = tid; idx < 64 * 33; idx += 256) {
        int e = idx / 33;
        featH[e][167 + idx % 33] = (half_t)0.f;
    }
    for (int idx = tid; idx < 4 * FROW; idx += 256) {
        featH[60 + idx / FROW][idx % FROW] = (half_t)0.f;
    }

    int e = tid >> 2, slot = tid & 3;
    if (e < 60) {
        int grow = row0 + (e >= KK ? 1 : 0);
        int ke = e - (e >= KK ? KK : 0);
        int i = grow & (LL - 1);
        int j = eidx_ws[grow * KK + ke];
        for (int task = slot; task < 11; task += 4) {
            if (task == 0) {
                int off = ridx[grow] - ridx[b * LL + j];
                int eq = (chl[grow] == chl[b * LL + j]) ? 1 : 0;
                int d = off + 32;
                d = d < 0 ? 0 : (d > 64 ? 64 : d);
                d = eq ? d : 65;
#pragma unroll
                for (int p = 0; p < 16; p++) featH[e][p] = (half_t)(posW[p * 66 + d] + posb[p]);
            } else if (task <= 9) {
                int q = task - 1;
                float D;
                if (q == 0) {
                    D = dnb_ws[grow * KK + ke];
                } else {
                    const int asel[8] = {0, 2, 0, 0, 1, 1, 2, 2};
                    const int bsel[8] = {0, 2, 1, 2, 0, 2, 0, 1};
                    float3 A = shiftedCa(Ca, b, i, asel[q - 1]);
                    float3 Bc = shiftedCa(Ca, b, j, bsel[q - 1]);
                    float dx = A.x - Bc.x, dy = A.y - Bc.y, dz = A.z - Bc.z;
                    D = sqrtf(dx * dx + dy * dy + dz * dz + 1e-6f);
                }
#pragma unroll
                for (int m = 0; m < 16; m++) {
                    float mu = 2.0f + (20.0f / 15.0f) * (float)m;
                    float tt = (D - mu) * 0.8f;
                    featH[e][16 + q * 16 + m] = (half_t)expf(-tt * tt);
                }
            } else {
                float Oi[9], Oj[9];
#pragma unroll
                for (int r = 0; r < 9; r++) {
                    Oi[r] = Of[(size_t)grow * 9 + r];
                    Oj[r] = Of[((size_t)(b * LL + j)) * 9 + r];
                }
                float3 cj = loadCa(Ca, b, j), cii = loadCa(Ca, b, i);
                float dx = cj.x - cii.x, dy = cj.y - cii.y, dz = cj.z - cii.z;
                float v0 = Oi[0] * dx + Oi[1] * dy + Oi[2] * dz;
                float v1 = Oi[3] * dx + Oi[4] * dy + Oi[5] * dz;
                float v2 = Oi[6] * dx + Oi[7] * dy + Oi[8] * dz;
                float nn = sqrtf(v0 * v0 + v1 * v1 + v2 * v2);
                float ninv = 1.f / fmaxf(nn, 1e-12f);
                featH[e][160] = (half_t)(v0 * ninv);
                featH[e][161] = (half_t)(v1 * ninv);
                featH[e][162] = (half_t)(v2 * ninv);
                float R[3][3];
#pragma unroll
                for (int m = 0; m < 3; m++)
#pragma unroll
                    for (int n = 0; n < 3; n++)
                        R[m][n] = Oi[0 * 3 + m] * Oj[0 * 3 + n] + Oi[1 * 3 + m] * Oj[1 * 3 + n] +
                                  Oi[2 * 3 + m] * Oj[2 * 3 + n];
                float Rxx = R[0][0], Ryy = R[1][1], Rzz = R[2][2];
                float m0 = 0.5f * sqrtf(fabsf(1.f + Rxx - Ryy - Rzz));
                float m1 = 0.5f * sqrtf(fabsf(1.f - Rxx + Ryy - Rzz));
                float m2 = 0.5f * sqrtf(fabsf(1.f - Rxx - Ryy + Rzz));
                float x = sgnf(R[2][1] - R[1][2]) * m0;
                float y = sgnf(R[0][2] - R[2][0]) * m1;
                float z = sgnf(R[1][0] - R[0][1]) * m2;
                float w = 0.5f * sqrtf(fmaxf(1.f + Rxx + Ryy + Rzz, 0.f));
                float qn = sqrtf(x * x + y * y + z * z + w * w);
                float qi = 1.f / fmaxf(qn, 1e-12f);
                featH[e][163] = (half_t)(x * qi);
                featH[e][164] = (half_t)(y * qi);
                featH[e][165] = (half_t)(z * qi);
                featH[e][166] = (half_t)(w * qi);
            }
        }
    }
    __syncthreads();

    int lane = tid & 63, w = tid >> 6;
    int col = lane & 15, g = lane >> 4;
    half8 af[6];
#pragma unroll
    for (int s = 0; s < 6; s++)
        af[s] = *(const half8*)&featH[16 * w + col][32 * s + 8 * g];
    f32x4 zero = {0.f, 0.f, 0.f, 0.f};
    f32x4 acc[8];
#pragma unroll
    for (int t = 0; t < 8; t++) acc[t] = zero;
#pragma unroll
    for (int t = 0; t < 8; t++) {
#pragma unroll
        for (int s = 0; s < 6; s++) {
            half8 bf = *(const half8*)(Bp + ((size_t)((t * 6 + s) * 64 + lane)) * 8);
            acc[t] = __builtin_amdgcn_mfma_f32_16x16x32_f16(af[s], bf, acc[t], 0, 0, 0);
        }
    }
    float mu[4], invs[4];
#pragma unroll
    for (int q = 0; q < 4; q++) {
        float s = 0.f;
#pragma unroll
        for (int t = 0; t < 8; t++) s += acc[t][q];
#pragma unroll
        for (int o = 1; o < 16; o <<= 1) s += __shfl_xor(s, o);
        mu[q] = s * (1.f / 128.f);
    }
#pragma unroll
    for (int q = 0; q < 4; q++) {
        float vs = 0.f;
#pragma unroll
        for (int t = 0; t < 8; t++) {
            float d = acc[t][q] - mu[q];
            vs += d * d;
        }
#pragma unroll
        for (int o = 1; o < 16; o <<= 1) vs += __shfl_xor(vs, o);
        invs[q] = 1.f / sqrtf(vs * (1.f / 128.f) + 1e-5f);
    }
    float lgv[8], lbv[8];
#pragma unroll
    for (int t = 0; t < 8; t++) {
        lgv[t] = ln_g[16 * t + col];
        lbv[t] = ln_b[16 * t + col];
    }
#pragma unroll
    for (int q = 0; q < 4; q++) {
        int eq = 16 * w + 4 * g + q;
        if (eq < 60) {
            int grow = row0 + (eq >= KK ? 1 : 0);
            int ke = eq - (eq >= KK ? KK : 0);
            float* dst = outE + ((size_t)(grow * KK + ke)) * CDIM + col;
#pragma unroll
            for (int t = 0; t < 8; t++)
                dst[16 * t] = (acc[t][q] - mu[q]) * invs[q] * lgv[t] + lbv[t];
        }
    }
}

extern "C" void kernel_launch(void* const* d_in, const int* in_sizes, int n_in,
                              void* d_out, int out_size, void* d_ws, size_t ws_size,
                              hipStream_t stream) {
    const float* Ca = (const float*)d_in[0];
    const float* mask = (const float*)d_in[1];
    const int* ridx = (const int*)d_in[2];
    const int* chl = (const int*)d_in[3];
    const float* posW = (const float*)d_in[4];
    const float* posb = (const float*)d_in[5];
    const float* edgeW = (const float*)d_in[6];
    const float* lng = (const float*)d_in[7];
    const float* lnb = (const float*)d_in[8];

    float* outE = (float*)d_out;
    float* outEidxF = outE + (size_t)NB * LL * KK * CDIM;

    char* ws = (char*)d_ws;
    half_t* Bp = (half_t*)ws;                             // 49152 B
    float* Of = (float*)(ws + 49152);                     // 294912 B
    int* eidx = (int*)(ws + 49152 + 294912);              // 983040 B
    float* dnb = (float*)(ws + 49152 + 294912 + 983040);  // 983040 B

    pack_kernel<<<12, 256, 0, stream>>>(edgeW, Bp);
    frames_kernel<<<(NB * LL + 255) / 256, 256, 0, stream>>>(Ca, Of);
    topk_kernel<<<NB * LL, 256, 0, stream>>>(Ca, mask, eidx, dnb, outEidxF);
    edge_kernel<<<NB * LL / 2, 256, 0, stream>>>(Ca, ridx, chl, posW, posb, Bp, lng, lnb,
                                                 Of, eidx, dnb, outE);
}

// Round 4
// 120.237 us; speedup vs baseline: 4.7088x; 1.0994x over previous
//
#include <hip/hip_runtime.h>
#include <stdint.h>

#define LL 4096
#define NB 2
#define KK 30
#define CDIM 128
#define FROW 200  // feat row stride in halves (400 B, multiple of 16 B)

typedef _Float16 half_t;
typedef half_t half8 __attribute__((ext_vector_type(8)));
typedef float f32x4 __attribute__((ext_vector_type(4)));

__device__ __forceinline__ float3 loadCa(const float* __restrict__ Ca, int b, int idx) {
    const float* p = Ca + ((size_t)(b * LL + idx)) * 3;
    return make_float3(p[0], p[1], p[2]);
}
__device__ __forceinline__ float3 shiftedCa(const float* __restrict__ Ca, int b, int idx, int sel) {
    int jj = idx + sel - 1;
    if (jj < 0 || jj >= LL) return make_float3(0.f, 0.f, 0.f);
    return loadCa(Ca, b, jj);
}
__device__ __forceinline__ float sgnf(float x) { return (x > 0.f) ? 1.f : ((x < 0.f) ? -1.f : 0.f); }

// ---------------- prep: W pack (f16 B-frags) + posW transpose + local frames ----------------
__global__ __launch_bounds__(256) void prep_kernel(const float* __restrict__ W,
                                                   const float* __restrict__ posW,
                                                   const float* __restrict__ posb,
                                                   const float* __restrict__ Ca,
                                                   half_t* __restrict__ Bp,
                                                   half_t* __restrict__ pwt,
                                                   float* __restrict__ Of) {
    int blk = blockIdx.x;
    int tid = threadIdx.x;
    if (blk < 12) {
        // Bp[((t*6+s)*64 + l)*8 + e] = W[n=16t+(l&15)][k=32s+8*(l>>4)+e], 0 if k>=167
        int idx = blk * 256 + tid;
        if (idx >= 8 * 6 * 64) return;
        int l = idx & 63;
        int ts = idx >> 6;
        int s = ts % 6, t = ts / 6;
        int n = 16 * t + (l & 15);
        int kbase = 32 * s + 8 * (l >> 4);
        half8 v;
#pragma unroll
        for (int e = 0; e < 8; e++) {
            int k = kbase + e;
            v[e] = (k < 167) ? (half_t)W[n * 167 + k] : (half_t)0.f;
        }
        *(half8*)(Bp + (size_t)idx * 8) = v;
    } else if (blk < 17) {
        int idx = (blk - 12) * 256 + tid;
        if (idx < 66 * 16) {
            int d = idx >> 4, p = idx & 15;
            pwt[d * 16 + p] = (half_t)(posW[p * 66 + d] + posb[p]);
        }
    } else {
        int t = (blk - 17) * 256 + tid;
        if (t >= NB * LL) return;
        int b = t >> 12, i = t & (LL - 1);
        float o[9] = {0.f, 0.f, 0.f, 0.f, 0.f, 0.f, 0.f, 0.f, 0.f};
        if (i >= 1 && i <= LL - 3) {
            float3 cm = loadCa(Ca, b, i - 1), cc = loadCa(Ca, b, i), cp = loadCa(Ca, b, i + 1);
            float dx0 = cc.x - cm.x, dy0 = cc.y - cm.y, dz0 = cc.z - cm.z;
            float n0 = sqrtf(dx0 * dx0 + dy0 * dy0 + dz0 * dz0);
            float k0 = (n0 > 3.6f && n0 < 4.0f) ? 1.f : 0.f;
            float s0 = k0 / fmaxf(n0 * k0, 1e-12f);
            float u2x = dx0 * s0, u2y = dy0 * s0, u2z = dz0 * s0;
            float dx1 = cp.x - cc.x, dy1 = cp.y - cc.y, dz1 = cp.z - cc.z;
            float n1 = sqrtf(dx1 * dx1 + dy1 * dy1 + dz1 * dz1);
            float k1 = (n1 > 3.6f && n1 < 4.0f) ? 1.f : 0.f;
            float s1 = k1 / fmaxf(n1 * k1, 1e-12f);
            float u1x = dx1 * s1, u1y = dy1 * s1, u1z = dz1 * s1;
            float cx = u2y * u1z - u2z * u1y;
            float cy = u2z * u1x - u2x * u1z;
            float cz = u2x * u1y - u2y * u1x;
            float cn = sqrtf(cx * cx + cy * cy + cz * cz);
            float cinv = 1.f / fmaxf(cn, 1e-12f);
            float n2x = cx * cinv, n2y = cy * cinv, n2z = cz * cinv;
            float ox = u2x - u1x, oy = u2y - u1y, oz = u2z - u1z;
            float on = sqrtf(ox * ox + oy * oy + oz * oz);
            float oinv = 1.f / fmaxf(on, 1e-12f);
            float o1x = ox * oinv, o1y = oy * oinv, o1z = oz * oinv;
            o[0] = o1x; o[1] = o1y; o[2] = o1z;
            o[3] = n2x; o[4] = n2y; o[5] = n2z;
            o[6] = o1y * n2z - o1z * n2y;
            o[7] = o1z * n2x - o1x * n2z;
            o[8] = o1x * n2y - o1y * n2x;
        }
        float* dst = Of + (size_t)t * 9;
#pragma unroll
        for (int r = 0; r < 9; r++) dst[r] = o[r];
    }
}

// ---------------- top-K per row: rank-select threshold + bitonic sort ----------------
__global__ __launch_bounds__(256, 8) void topk_kernel(const float* __restrict__ Ca,
                                                      const float* __restrict__ mask,
                                                      int* __restrict__ eidx_ws,
                                                      float* __restrict__ dnb_ws,
                                                      float* __restrict__ out_eidx_f) {
    __shared__ unsigned long long cand[512];
    __shared__ int wint[2][4];
    __shared__ float wflt[4];
    int row = blockIdx.x;
    int b = row >> 12;
    int tid = threadIdx.x;
    int w = tid >> 6, lane = tid & 63;
    float3 ci = loadCa(Ca, b, row & (LL - 1));
    float mi = mask[row];
    float dreg[16];
    float localmax = 0.f;
#pragma unroll
    for (int s = 0; s < 16; s++) {
        int j = tid + s * 256;
        const float* pj = Ca + ((size_t)(b * LL + j)) * 3;
        float dx = pj[0] - ci.x, dy = pj[1] - ci.y, dz = pj[2] - ci.z;
        float d = sqrtf(dx * dx + dy * dy + dz * dz + 1e-6f);
        float D = mi * mask[b * LL + j] * d;
        dreg[s] = D;
        localmax = fmaxf(localmax, D);
    }
#pragma unroll
    for (int o = 32; o; o >>= 1) localmax = fmaxf(localmax, __shfl_xor(localmax, o));
    if (lane == 0) wflt[w] = localmax;
    __syncthreads();
    float dmax = fmaxf(fmaxf(wflt[0], wflt[1]), fmaxf(wflt[2], wflt[3]));
    unsigned ui[16];
#pragma unroll
    for (int s = 0; s < 16; s++) {
        int j = tid + s * 256;
        float m2 = mi * mask[b * LL + j];
        ui[s] = __float_as_uint(dreg[s] + (1.0f - m2) * dmax);
    }
    unsigned lo = 0u, hi = 0x7f800000u, T = 0u;
    bool found = false;
    int p = 0;
    for (int it = 0; it < 24 && !found; ++it) {
        unsigned mid = (lo + hi) >> 1;
        int c = 0;
#pragma unroll
        for (int s = 0; s < 16; s++) c += (ui[s] < mid) ? 1 : 0;
#pragma unroll
        for (int o = 32; o; o >>= 1) c += __shfl_xor(c, o);
        if (lane == 0) wint[p][w] = c;
        __syncthreads();
        c = wint[p][0] + wint[p][1] + wint[p][2] + wint[p][3];
        p ^= 1;
        if (c < 30) lo = mid;
        else if (c > 64) hi = mid;
        else { T = mid; found = true; }
    }
    if (!found) T = hi;
    int cnt = 0;
#pragma unroll
    for (int s = 0; s < 16; s++) cnt += (ui[s] < T) ? 1 : 0;
    int inc = cnt;
#pragma unroll
    for (int o = 1; o < 64; o <<= 1) {
        int nv = __shfl_up(inc, o);
        if (lane >= o) inc += nv;
    }
    if (lane == 63) wint[0][w] = inc;
    __syncthreads();
    int C = wint[0][0] + wint[0][1] + wint[0][2] + wint[0][3];
    int waveoff = 0;
    for (int q = 0; q < 4; q++) waveoff += (q < w) ? wint[0][q] : 0;
    int slot = waveoff + inc - cnt;
#pragma unroll
    for (int s = 0; s < 16; s++) {
        if (ui[s] < T) {
            int j = tid + s * 256;
            if (slot < 512)
                cand[slot] = ((unsigned long long)ui[s] << 32) | (unsigned)j;
            slot++;
        }
    }
    __syncthreads();
    if (w != 0) return;
    if (C <= 64) {
        unsigned long long v = (lane < C) ? cand[lane] : ~0ull;
#pragma unroll
        for (int k = 2; k <= 64; k <<= 1) {
#pragma unroll
            for (int jj = k >> 1; jj > 0; jj >>= 1) {
                unsigned long long o = __shfl_xor(v, jj);
                bool take_min = (((lane & jj) == 0) == ((lane & k) == 0));
                bool lt = (o < v);
                v = (take_min == lt) ? o : v;
            }
        }
        if (lane < KK) {
            int j = (int)(v & 0xffffffffu);
            eidx_ws[row * KK + lane] = j;
            dnb_ws[row * KK + lane] = __uint_as_float((unsigned)(v >> 32));
            out_eidx_f[row * KK + lane] = (float)j;
        }
    } else {
        unsigned long long r[8];
#pragma unroll
        for (int q = 0; q < 8; q++) {
            int idx = lane + 64 * q;
            r[q] = (idx < C && idx < 512) ? cand[idx] : ~0ull;
        }
        for (int t = 0; t < KK; t++) {
            unsigned long long v = r[0];
#pragma unroll
            for (int q = 1; q < 8; q++) v = (r[q] < v) ? r[q] : v;
#pragma unroll
            for (int o = 32; o; o >>= 1) {
                unsigned long long u = __shfl_xor(v, o);
                if (u < v) v = u;
            }
            if (lane == 0) {
                int j = (int)(v & 0xffffffffu);
                eidx_ws[row * KK + t] = j;
                dnb_ws[row * KK + t] = __uint_as_float((unsigned)(v >> 32));
                out_eidx_f[row * KK + t] = (float)j;
            }
#pragma unroll
            for (int q = 0; q < 8; q++)
                if (r[q] == v) r[q] = ~0ull;
        }
    }
}

// ---------------- edge feature jobs ----------------
__device__ __forceinline__ void rbf_job(int job, int row0, int b,
                                        const float* __restrict__ Ca,
                                        const int* __restrict__ eidx_ws,
                                        const float* __restrict__ dnb_ws,
                                        half_t (*featH)[FROW]) {
    int e = job / 9;
    int q = job - e * 9;
    int isr1 = (e >= KK) ? 1 : 0;
    int grow = row0 + isr1;
    int ke = e - (isr1 ? KK : 0);
    int i = grow & (LL - 1);
    int j = eidx_ws[grow * KK + ke];
    float D;
    if (q == 0) {
        D = dnb_ws[grow * KK + ke];
    } else {
        const int asel[8] = {0, 2, 0, 0, 1, 1, 2, 2};
        const int bsel[8] = {0, 2, 1, 2, 0, 2, 0, 1};
        float3 A = shiftedCa(Ca, b, i, asel[q - 1]);
        float3 Bc = shiftedCa(Ca, b, j, bsel[q - 1]);
        float dx = A.x - Bc.x, dy = A.y - Bc.y, dz = A.z - Bc.z;
        D = sqrtf(dx * dx + dy * dy + dz * dz + 1e-6f);
    }
    half8 v0, v1;
#pragma unroll
    for (int m = 0; m < 8; m++) {
        float mu = 2.0f + (4.f / 3.f) * (float)m;
        float t = (D - mu) * 0.8f;
        v0[m] = (half_t)exp2f(t * t * -1.4426950408889634f);
    }
#pragma unroll
    for (int m = 8; m < 16; m++) {
        float mu = 2.0f + (4.f / 3.f) * (float)m;
        float t = (D - mu) * 0.8f;
        v1[m - 8] = (half_t)exp2f(t * t * -1.4426950408889634f);
    }
    *(half8*)&featH[e][16 + 16 * q] = v0;
    *(half8*)&featH[e][24 + 16 * q] = v1;
}

__device__ __forceinline__ void pos_job(int e, int row0, int b,
                                        const int* __restrict__ ridx,
                                        const int* __restrict__ chl,
                                        const half_t* __restrict__ pwt,
                                        const int* __restrict__ eidx_ws,
                                        half_t (*featH)[FROW]) {
    int isr1 = (e >= KK) ? 1 : 0;
    int grow = row0 + isr1;
    int ke = e - (isr1 ? KK : 0);
    int j = eidx_ws[grow * KK + ke];
    int off = ridx[grow] - ridx[b * LL + j];
    int eq = (chl[grow] == chl[b * LL + j]) ? 1 : 0;
    int d = off + 32;
    d = d < 0 ? 0 : (d > 64 ? 64 : d);
    d = eq ? d : 65;
    *(half8*)&featH[e][0] = *(const half8*)(pwt + d * 16);
    *(half8*)&featH[e][8] = *(const half8*)(pwt + d * 16 + 8);
}

__device__ __forceinline__ void orient_job(int e, int row0, int b,
                                           const float* __restrict__ Ca,
                                           const float* __restrict__ Of,
                                           const int* __restrict__ eidx_ws,
                                           half_t (*featH)[FROW]) {
    int isr1 = (e >= KK) ? 1 : 0;
    int grow = row0 + isr1;
    int ke = e - (isr1 ? KK : 0);
    int i = grow & (LL - 1);
    int j = eidx_ws[grow * KK + ke];
    float Oi[9], Oj[9];
#pragma unroll
    for (int r = 0; r < 9; r++) {
        Oi[r] = Of[(size_t)grow * 9 + r];
        Oj[r] = Of[((size_t)(b * LL + j)) * 9 + r];
    }
    float3 cj = loadCa(Ca, b, j), cii = loadCa(Ca, b, i);
    float dx = cj.x - cii.x, dy = cj.y - cii.y, dz = cj.z - cii.z;
    float v0 = Oi[0] * dx + Oi[1] * dy + Oi[2] * dz;
    float v1 = Oi[3] * dx + Oi[4] * dy + Oi[5] * dz;
    float v2 = Oi[6] * dx + Oi[7] * dy + Oi[8] * dz;
    float nn = sqrtf(v0 * v0 + v1 * v1 + v2 * v2);
    float ninv = 1.f / fmaxf(nn, 1e-12f);
    float R[3][3];
#pragma unroll
    for (int m = 0; m < 3; m++)
#pragma unroll
        for (int n = 0; n < 3; n++)
            R[m][n] = Oi[0 * 3 + m] * Oj[0 * 3 + n] + Oi[1 * 3 + m] * Oj[1 * 3 + n] +
                      Oi[2 * 3 + m] * Oj[2 * 3 + n];
    float Rxx = R[0][0], Ryy = R[1][1], Rzz = R[2][2];
    float m0 = 0.5f * sqrtf(fabsf(1.f + Rxx - Ryy - Rzz));
    float m1 = 0.5f * sqrtf(fabsf(1.f - Rxx + Ryy - Rzz));
    float m2 = 0.5f * sqrtf(fabsf(1.f - Rxx - Ryy + Rzz));
    float x = sgnf(R[2][1] - R[1][2]) * m0;
    float y = sgnf(R[0][2] - R[2][0]) * m1;
    float z = sgnf(R[1][0] - R[0][1]) * m2;
    float w = 0.5f * sqrtf(fmaxf(1.f + Rxx + Ryy + Rzz, 0.f));
    float qn = sqrtf(x * x + y * y + z * z + w * w);
    float qi = 1.f / fmaxf(qn, 1e-12f);
    half8 h;
    h[0] = (half_t)(v0 * ninv);
    h[1] = (half_t)(v1 * ninv);
    h[2] = (half_t)(v2 * ninv);
    h[3] = (half_t)(x * qi);
    h[4] = (half_t)(y * qi);
    h[5] = (half_t)(z * qi);
    h[6] = (half_t)(w * qi);
    h[7] = (half_t)0.f;
    half8 zv = {};
    *(half8*)&featH[e][160] = h;
    *(half8*)&featH[e][168] = zv;
    *(half8*)&featH[e][176] = zv;
    *(half8*)&featH[e][184] = zv;
    *(half8*)&featH[e][192] = zv;
}

// ---------------- features (f16, LDS) + MFMA 64x128x192 + LayerNorm ----------------
__global__ __launch_bounds__(256) void edge_kernel(const float* __restrict__ Ca,
                                                   const int* __restrict__ ridx,
                                                   const int* __restrict__ chl,
                                                   const half_t* __restrict__ pwt,
                                                   const half_t* __restrict__ Bp,
                                                   const float* __restrict__ ln_g,
                                                   const float* __restrict__ ln_b,
                                                   const float* __restrict__ Of,
                                                   const int* __restrict__ eidx_ws,
                                                   const float* __restrict__ dnb_ws,
                                                   float* __restrict__ outE) {
    __shared__ alignas(16) half_t featH[64][FROW];
    int row0 = blockIdx.x * 2;
    int b = row0 >> 12;
    int tid = threadIdx.x;

    // pass A + B: fully uniform RBF jobs
    rbf_job(tid, row0, b, Ca, eidx_ws, dnb_ws, featH);
    rbf_job(256 + tid, row0, b, Ca, eidx_ws, dnb_ws, featH);
    // pass C: remaining RBF + positional + orientation + zero rows
    if (tid < 28) {
        rbf_job(512 + tid, row0, b, Ca, eidx_ws, dnb_ws, featH);
    } else if (tid >= 32 && tid < 92) {
        pos_job(tid - 32, row0, b, ridx, chl, pwt, eidx_ws, featH);
    } else if (tid >= 96 && tid < 156) {
        orient_job(tid - 96, row0, b, Ca, Of, eidx_ws, featH);
    } else if (tid >= 156) {
        int t = tid - 156;  // 0..99: zero rows 60..63 (25 half8 chunks each)
        int r = 60 + t / 25, c = t % 25;
        half8 zv = {};
        *(half8*)&featH[r][c * 8] = zv;
    }
    __syncthreads();

    int lane = tid & 63, w = tid >> 6;
    int col = lane & 15, g = lane >> 4;
    half8 af[6];
#pragma unroll
    for (int s = 0; s < 6; s++)
        af[s] = *(const half8*)&featH[16 * w + col][32 * s + 8 * g];
    f32x4 zero = {0.f, 0.f, 0.f, 0.f};
    f32x4 acc[8];
#pragma unroll
    for (int t = 0; t < 8; t++) acc[t] = zero;
#pragma unroll
    for (int t = 0; t < 8; t++) {
#pragma unroll
        for (int s = 0; s < 6; s++) {
            half8 bf = *(const half8*)(Bp + ((size_t)((t * 6 + s) * 64 + lane)) * 8);
            acc[t] = __builtin_amdgcn_mfma_f32_16x16x32_f16(af[s], bf, acc[t], 0, 0, 0);
        }
    }
    float mu[4], invs[4];
#pragma unroll
    for (int q = 0; q < 4; q++) {
        float s = 0.f;
#pragma unroll
        for (int t = 0; t < 8; t++) s += acc[t][q];
#pragma unroll
        for (int o = 1; o < 16; o <<= 1) s += __shfl_xor(s, o);
        mu[q] = s * (1.f / 128.f);
    }
#pragma unroll
    for (int q = 0; q < 4; q++) {
        float vs = 0.f;
#pragma unroll
        for (int t = 0; t < 8; t++) {
            float d = acc[t][q] - mu[q];
            vs += d * d;
        }
#pragma unroll
        for (int o = 1; o < 16; o <<= 1) vs += __shfl_xor(vs, o);
        invs[q] = 1.f / sqrtf(vs * (1.f / 128.f) + 1e-5f);
    }
    float lgv[8], lbv[8];
#pragma unroll
    for (int t = 0; t < 8; t++) {
        lgv[t] = ln_g[16 * t + col];
        lbv[t] = ln_b[16 * t + col];
    }
#pragma unroll
    for (int q = 0; q < 4; q++) {
        int eq = 16 * w + 4 * g + q;
        if (eq < 60) {
            int grow = row0 + (eq >= KK ? 1 : 0);
            int ke = eq - (eq >= KK ? KK : 0);
            float* dst = outE + ((size_t)(grow * KK + ke)) * CDIM + col;
#pragma unroll
            for (int t = 0; t < 8; t++)
                dst[16 * t] = (acc[t][q] - mu[q]) * invs[q] * lgv[t] + lbv[t];
        }
    }
}

extern "C" void kernel_launch(void* const* d_in, const int* in_sizes, int n_in,
                              void* d_out, int out_size, void* d_ws, size_t ws_size,
                              hipStream_t stream) {
    const float* Ca = (const float*)d_in[0];
    const float* mask = (const float*)d_in[1];
    const int* ridx = (const int*)d_in[2];
    const int* chl = (const int*)d_in[3];
    const float* posW = (const float*)d_in[4];
    const float* posb = (const float*)d_in[5];
    const float* edgeW = (const float*)d_in[6];
    const float* lng = (const float*)d_in[7];
    const float* lnb = (const float*)d_in[8];

    float* outE = (float*)d_out;
    float* outEidxF = outE + (size_t)NB * LL * KK * CDIM;

    char* ws = (char*)d_ws;
    half_t* Bp = (half_t*)ws;                     // 49152 B
    half_t* pwt = (half_t*)(ws + 49152);          // 66*16*2 = 2112 B
    float* Of = (float*)(ws + 51264);             // 294912 B
    int* eidx = (int*)(ws + 346176);              // 983040 B
    float* dnb = (float*)(ws + 1329216);          // 983040 B

    prep_kernel<<<17 + (NB * LL + 255) / 256, 256, 0, stream>>>(edgeW, posW, posb, Ca, Bp, pwt, Of);
    topk_kernel<<<NB * LL, 256, 0, stream>>>(Ca, mask, eidx, dnb, outEidxF);
    edge_kernel<<<NB * LL / 2, 256, 0, stream>>>(Ca, ridx, chl, pwt, Bp, lng, lnb,
                                                 Of, eidx, dnb, outE);
}